// Round 4
// baseline (2219.184 us; speedup 1.0000x reference)
//
#include <hip/hip_runtime.h>

// HWTV: ADMM TV solver, 124 independent 128x128 images, 20 iterations.
// One workgroup per image; whole iteration loop in-kernel.
// Round 7: stop fighting the 64-VGPR cap -- design for it. R4-R6 proved the
// toolchain pins this kernel at 64 VGPRs regardless of launch_bounds /
// waves_per_eu / static-LDS occupancy hints, so the 48 persistent
// floats/thread (g1, bh, bv across the FFT) always spilled to scratch
// (~1.3 GB HBM round-trips). R7 does the "spill" by hand:
//   - (bh,bv) -> float2 plane in d_ws. Written in P1 (volatile b64),
//     reloaded in P2 for LDS staging and next iteration's P1. Same-thread
//     addresses only -> no fences needed. ~16 MB working set, L2-resident.
//   - g1 -> plane aliased onto outg (same size; all g1 stores are dead by
//     the final iteration's out write). Volatile so DSE can't delete them.
//   - a = mu1*X+G1 still rides C[p].y across the iteration boundary.
// Volatile is LOAD-BEARING: without it the compiler store-forwards the
// same-thread store->load pairs, keeps 48 values live across the FFT, and
// re-spills to scratch. Peak live regs anywhere is now ~40 -> fits 64.
// FFT: radix-2 DIF forward (bit-rev out) -> pointwise solve with bit-rev
// denom table -> radix-2 DIT inverse (bit-rev in). 1/N^2 folded into solve.

#define NPIX   16384
#define NSIDE  128
#define NIMG   124
#define NT     1024
#define PXT    16          // pixels per thread
#define N_ITE  20
#define LAM_F  0.1f
#define RHO_F  1.05f
#define PI_F   3.14159265358979323846f

__device__ __forceinline__ void bfly_fwd(float2& A, float2& B, float wr, float wi) {
    float ar = A.x, ai = A.y, br = B.x, bi = B.y;
    A.x = ar + br; A.y = ai + bi;
    float tr = ar - br, ti = ai - bi;
    B.x = tr * wr - ti * wi;
    B.y = tr * wi + ti * wr;
}

__device__ __forceinline__ void bfly_inv(float2& A, float2& B, float wr, float wi) {
    // b * conj(w), then a+b / a-b
    float ar = A.x, ai = A.y, br = B.x, bi = B.y;
    float pr = br * wr + bi * wi;
    float pi = bi * wr - br * wi;
    A.x = ar + pr; A.y = ai + pi;
    B.x = ar - pr; B.y = ai - pi;
}

// volatile 8-byte plane accessors (single dwordx2, not elidable/forwardable)
__device__ __forceinline__ float2 vload_f2(const float2* a) {
    union { long long l; float2 f; } u;
    u.l = *(const volatile long long*)a;
    return u.f;
}
__device__ __forceinline__ void vstore_f2(float2* a, float2 v) {
    union { long long l; float2 f; } u;
    u.f = v;
    *(volatile long long*)a = u.l;
}

__global__ __launch_bounds__(NT) void hwtv_kernel(
    const float* __restrict__ Yg,
    const float* __restrict__ Wg,
    float* __restrict__ outg,
    float2* __restrict__ bhvg)
{
    __shared__ float2 C[NPIX];     // 128 KB
    __shared__ float2 TW[64];      // twiddles W_128^k
    __shared__ float  D1[NSIDE];   // 4sin^2(pi*bitrev7(i)/128)

    const int tid = threadIdx.x;
    const size_t base  = (size_t)blockIdx.x * NPIX;
    const float* Y  = Yg + base;
    const float* Wt = Wg + base;
    float* g1p  = outg + base;      // g1 plane, doubles as final output
    float2* bhv = bhvg + base;      // (bh, bv) plane in workspace

    // ---- one-time tables + Z0 = Y into LDS ----
    if (tid < 64) {
        float ang = -2.0f * PI_F * (float)tid / 128.0f;
        TW[tid] = make_float2(cosf(ang), sinf(ang));
    }
    if (tid < 128) {
        int br = (int)(__brev((unsigned)tid) >> 25);       // bitrev7
        float s = sinf(PI_F * (float)br / 128.0f);
        D1[tid] = 4.0f * s * s;
    }

    #pragma unroll
    for (int k = 0; k < PXT; ++k) {
        int p = tid + k * NT;
        float y = Y[p];
        C[p] = make_float2(y, 0.1f * y);  // Z0 = Y ; .y = a0 = mu1*X0 + G1_0
    }
    __syncthreads();

    float mu1 = 0.1f, mu2 = 0.1f;

    for (int it = 0; it < N_ITE; ++it) {
        const float mu2p   = mu2 * (1.0f / RHO_F);  // previous iteration's mu2
        const float inv_m2 = 1.0f / mu2;
        const float thr    = LAM_F * inv_m2;

        // ---- P1: shrink; write (bh,bv) = (mu2*Uh+G21, mu2*Uv+G22) to the
        //      global plane. Z in C[].x; a (prev epilogue) in C[].y. ----
        float areg[PXT];
        #pragma unroll
        for (int k = 0; k < PXT; ++k) {
            int p    = tid + k * NT;
            int col  = p & (NSIDE - 1);
            int rowb = p & ~(NSIDE - 1);
            float2 zc = C[p];
            float z  = zc.x;
            areg[k]  = zc.y;
            float zl = C[rowb | ((col + NSIDE - 1) & (NSIDE - 1))].x;
            float zu = C[(p + NPIX - NSIDE) & (NPIX - 1)].x;
            float dhz = z - zl;
            float dvz = z - zu;
            float g21 = 0.0f, g22 = 0.0f;
            if (it != 0) {
                float2 bo = vload_f2(bhv + p);        // own addr, L2 hit
                g21 = fmaf(-mu2p, dhz, bo.x);
                g22 = fmaf(-mu2p, dvz, bo.y);
            }
            float ah = dhz - g21 * inv_m2;
            float av = dvz - g22 * inv_m2;
            float uh = copysignf(fmaxf(fabsf(ah) - thr, 0.0f), ah);
            float uv = copysignf(fmaxf(fabsf(av) - thr, 0.0f), av);
            vstore_f2(bhv + p, make_float2(fmaf(mu2, uh, g21),
                                           fmaf(mu2, uv, g22)));
        }
        __syncthreads();          // all Z reads done before overwriting C

        // ---- P2: reload (bh,bv) from plane, stage in C for neighbor
        //      exchange (keeps bh/bv out of registers across barriers) ----
        #pragma unroll
        for (int k = 0; k < PXT; ++k) {
            int p = tid + k * NT;
            C[p] = vload_f2(bhv + p);
        }
        __syncthreads();

        // ---- P3: numerator = a + Dh^T bh + Dv^T bv ----
        float numv[PXT];
        #pragma unroll
        for (int k = 0; k < PXT; ++k) {
            int p    = tid + k * NT;
            int col  = p & (NSIDE - 1);
            int rowb = p & ~(NSIDE - 1);
            float2 own = C[p];
            float bhr = C[rowb | ((col + 1) & (NSIDE - 1))].x;
            float bvd = C[(p + NSIDE) & (NPIX - 1)].y;
            numv[k] = areg[k] + (own.x - bhr) + (own.y - bvd);
        }
        __syncthreads();          // all neighbor reads done before overwrite

        // ---- P4: C <- numerator (real) ----
        #pragma unroll
        for (int k = 0; k < PXT; ++k) {
            int p = tid + k * NT;
            C[p] = make_float2(numv[k], 0.0f);
        }
        __syncthreads();

        // ---- forward FFT over rows (DIF, natural in -> bit-rev out) ----
        for (int s = 0; s < 7; ++s) {
            const int len = 64 >> s;
            #pragma unroll 4
            for (int q = 0; q < 8; ++q) {
                int tau = tid + q * NT;            // 0..8191
                int t   = tau & 63;                // butterfly within row
                int org = (tau >> 6) << 7;         // row * 128
                int j   = t & (len - 1);
                int i0  = ((t ^ j) << 1) | j;
                float2 w = TW[j << s];
                float2 A = C[org + i0];
                float2 B = C[org + i0 + len];
                bfly_fwd(A, B, w.x, w.y);
                C[org + i0]       = A;
                C[org + i0 + len] = B;
            }
            __syncthreads();
        }
        // ---- forward FFT over cols (DIF) ----
        for (int s = 0; s < 7; ++s) {
            const int len = 64 >> s;
            #pragma unroll 4
            for (int q = 0; q < 8; ++q) {
                int tau = tid + q * NT;
                int c   = tau & (NSIDE - 1);
                int t   = tau >> 7;                // 0..63
                int j   = t & (len - 1);
                int i0  = ((t ^ j) << 1) | j;
                int b0  = i0 * NSIDE + c;
                float2 w = TW[j << s];
                float2 A = C[b0];
                float2 B = C[b0 + len * NSIDE];
                bfly_fwd(A, B, w.x, w.y);
                C[b0]               = A;
                C[b0 + len * NSIDE] = B;
            }
            __syncthreads();
        }

        // ---- pointwise Fourier solve (bit-rev indexed), 1/N^2 folded in ----
        {
            const float sc = 1.0f / (float)NPIX;
            #pragma unroll
            for (int k = 0; k < PXT; ++k) {
                int p = tid + k * NT;
                float den = mu1 + mu2 * (D1[p >> 7] + D1[p & (NSIDE - 1)]);
                float f = sc / den;
                float2 v = C[p];
                C[p] = make_float2(v.x * f, v.y * f);
            }
            __syncthreads();
        }

        // ---- inverse FFT over cols (DIT, bit-rev in -> natural out) ----
        for (int s = 0; s < 7; ++s) {
            const int len = 1 << s;
            #pragma unroll 4
            for (int q = 0; q < 8; ++q) {
                int tau = tid + q * NT;
                int c   = tau & (NSIDE - 1);
                int t   = tau >> 7;
                int j   = t & (len - 1);
                int i0  = ((t ^ j) << 1) | j;
                int b0  = i0 * NSIDE + c;
                float2 w = TW[j << (6 - s)];
                float2 A = C[b0];
                float2 B = C[b0 + len * NSIDE];
                bfly_inv(A, B, w.x, w.y);
                C[b0]               = A;
                C[b0 + len * NSIDE] = B;
            }
            __syncthreads();
        }
        // ---- inverse FFT over rows (DIT) ----
        for (int s = 0; s < 7; ++s) {
            const int len = 1 << s;
            #pragma unroll 4
            for (int q = 0; q < 8; ++q) {
                int tau = tid + q * NT;
                int t   = tau & 63;
                int org = (tau >> 6) << 7;
                int j   = t & (len - 1);
                int i0  = ((t ^ j) << 1) | j;
                float2 w = TW[j << (6 - s)];
                float2 A = C[org + i0];
                float2 B = C[org + i0 + len];
                bfly_inv(A, B, w.x, w.y);
                C[org + i0]       = A;
                C[org + i0 + len] = B;
            }
            __syncthreads();
        }

        // ---- Epilogue: X/G1 update; g1 round-trips through the outg plane
        //      (volatile); Z stays in C[].x; a stash in C[].y. On the last
        //      iteration the plane store becomes the real output (z). ----
        const float mu1n = mu1 * RHO_F;
        const bool  last = (it == N_ITE - 1);
        #pragma unroll
        for (int k = 0; k < PXT; ++k) {
            int p = tid + k * NT;
            float z  = C[p].x;
            float y  = Y[p];
            float w  = Wt[p];
            float g1o = (it == 0) ? 0.0f : *(volatile float*)(g1p + p);
            float x  = fmaf(w, y, fmaf(mu1, z, -g1o)) *
                       __builtin_amdgcn_rcpf(w + mu1);
            float g1n = fmaf(mu1, x - z, g1o);
            *(volatile float*)(g1p + p) = last ? z : g1n;
            ((float*)(C + p))[1] = fmaf(mu1n, x, g1n);   // stash a for next P1
        }
        // no barrier needed: next P1's neighbor reads touch only .x (unchanged
        // since the last FFT barrier); the .y stash is same-thread; P2's
        // overwrites are behind P1's barrier.

        mu1 *= RHO_F;
        mu2 *= RHO_F;
    }
}

extern "C" void kernel_launch(void* const* d_in, const int* in_sizes, int n_in,
                              void* d_out, int out_size, void* d_ws, size_t ws_size,
                              hipStream_t stream) {
    (void)in_sizes; (void)n_in; (void)out_size; (void)ws_size;
    const float* Y   = (const float*)d_in[0];
    const float* inW = (const float*)d_in[1];
    float* out = (float*)d_out;
    float2* bhv = (float2*)d_ws;    // needs NIMG*NPIX*8 = 16.25 MB

    hipLaunchKernelGGL(hwtv_kernel, dim3(NIMG), dim3(NT), 0, stream,
                       Y, inW, out, bhv);
}

// Round 5
// 2093.878 us; speedup vs baseline: 1.0598x; 1.0598x over previous
//
#include <hip/hip_runtime.h>

// HWTV: ADMM TV solver, 124 independent 128x128 images, 20 iterations.
// One workgroup per image; whole iteration loop in-kernel.
// Round 8: hand-spill, done right. History:
//   R4-R6: compiler pins 64 VGPRs (launch_bounds/waves_per_eu/static-LDS all
//          ignored); 48 persistent floats/thread spilled to scratch (~1.3 GB
//          HBM round-trips).
//   R7: volatile planes -> gfx950 volatile codegen is system-scope (sc0/sc1),
//       bypasses L2 -> every plane access went to HBM; WORSE (2219 us).
// R8 keeps the plane architecture but accesses them with inline-asm
// global_load/global_store: NORMAL caching (L2-resident, ~3 MB/XCD working
// set) but OPAQUE to the compiler (no store-forwarding, no live-range
// resurrection, no scratch). Loads carry a leading s_waitcnt vmcnt(0)
// (GCN gives no same-thread store->load ordering without draining) and a
// trailing one (result usable immediately; compiler can't track asm vmcnt).
// Planes: (bh,bv) float2 in d_ws; g1 aliased onto outg (all g1 stores dead
// by the final iteration's z write -- mechanism validated in R7).
// a = mu1*X+G1 rides C[p].y across the iteration boundary.
// Peak live regs now ~30 (FFT transients only) -> fits the 64-VGPR cap with
// nothing left to spill.
// FFT: radix-2 DIF forward (bit-rev out) -> pointwise solve with bit-rev
// denom table -> radix-2 DIT inverse (bit-rev in). 1/N^2 folded into solve.

#define NPIX   16384
#define NSIDE  128
#define NIMG   124
#define NT     1024
#define PXT    16          // pixels per thread
#define N_ITE  20
#define LAM_F  0.1f
#define RHO_F  1.05f
#define PI_F   3.14159265358979323846f

typedef float f32x2 __attribute__((ext_vector_type(2)));

__device__ __forceinline__ void bfly_fwd(float2& A, float2& B, float wr, float wi) {
    float ar = A.x, ai = A.y, br = B.x, bi = B.y;
    A.x = ar + br; A.y = ai + bi;
    float tr = ar - br, ti = ai - bi;
    B.x = tr * wr - ti * wi;
    B.y = tr * wi + ti * wr;
}

__device__ __forceinline__ void bfly_inv(float2& A, float2& B, float wr, float wi) {
    // b * conj(w), then a+b / a-b
    float ar = A.x, ai = A.y, br = B.x, bi = B.y;
    float pr = br * wr + bi * wi;
    float pi = bi * wr - br * wi;
    A.x = ar + pr; A.y = ai + pi;
    B.x = ar - pr; B.y = ai - pi;
}

// ---- opaque, cached plane accessors ----
__device__ __forceinline__ f32x2 gload_f2(const void* a) {
    f32x2 r;
    asm volatile("s_waitcnt vmcnt(0)\n\t"
                 "global_load_dwordx2 %0, %1, off\n\t"
                 "s_waitcnt vmcnt(0)"
                 : "=v"(r) : "v"(a) : "memory");
    return r;
}
__device__ __forceinline__ void gstore_f2(void* a, f32x2 v) {
    asm volatile("global_store_dwordx2 %0, %1, off"
                 :: "v"(a), "v"(v) : "memory");
}
__device__ __forceinline__ float gload_f1(const void* a) {
    float r;
    asm volatile("s_waitcnt vmcnt(0)\n\t"
                 "global_load_dword %0, %1, off\n\t"
                 "s_waitcnt vmcnt(0)"
                 : "=v"(r) : "v"(a) : "memory");
    return r;
}
__device__ __forceinline__ void gstore_f1(void* a, float v) {
    asm volatile("global_store_dword %0, %1, off"
                 :: "v"(a), "v"(v) : "memory");
}

__global__ __launch_bounds__(NT) void hwtv_kernel(
    const float* __restrict__ Yg,
    const float* __restrict__ Wg,
    float* __restrict__ outg,
    f32x2* __restrict__ bhvg)
{
    __shared__ float2 C[NPIX];     // 128 KB
    __shared__ float2 TW[64];      // twiddles W_128^k
    __shared__ float  D1[NSIDE];   // 4sin^2(pi*bitrev7(i)/128)

    const int tid = threadIdx.x;
    const size_t base  = (size_t)blockIdx.x * NPIX;
    const float* Y  = Yg + base;
    const float* Wt = Wg + base;
    float* g1p  = outg + base;      // g1 plane, doubles as final output
    f32x2* bhv  = bhvg + base;      // (bh, bv) plane in workspace

    // ---- one-time tables + Z0 = Y into LDS ----
    if (tid < 64) {
        float ang = -2.0f * PI_F * (float)tid / 128.0f;
        TW[tid] = make_float2(cosf(ang), sinf(ang));
    }
    if (tid < 128) {
        int br = (int)(__brev((unsigned)tid) >> 25);       // bitrev7
        float s = sinf(PI_F * (float)br / 128.0f);
        D1[tid] = 4.0f * s * s;
    }

    #pragma unroll
    for (int k = 0; k < PXT; ++k) {
        int p = tid + k * NT;
        float y = Y[p];
        C[p] = make_float2(y, 0.1f * y);  // Z0 = Y ; .y = a0 = mu1*X0 + G1_0
    }
    __syncthreads();

    float mu1 = 0.1f, mu2 = 0.1f;

    for (int it = 0; it < N_ITE; ++it) {
        const float mu2p   = mu2 * (1.0f / RHO_F);  // previous iteration's mu2
        const float inv_m2 = 1.0f / mu2;
        const float thr    = LAM_F * inv_m2;

        // ---- P1: shrink; (bh,bv) = (mu2*Uh+G21, mu2*Uv+G22) -> plane ----
        // Z in C[].x; a (prev epilogue) in C[].y (own pixel only).
        // G21 = bh_old - mu2_prev*DhZ (DhZ of current Z).
        float areg[PXT];
        #pragma unroll
        for (int k = 0; k < PXT; ++k) {
            int p    = tid + k * NT;
            int col  = p & (NSIDE - 1);
            int rowb = p & ~(NSIDE - 1);
            float2 zc = C[p];
            float z  = zc.x;
            areg[k]  = zc.y;
            float zl = C[rowb | ((col + NSIDE - 1) & (NSIDE - 1))].x;
            float zu = C[(p + NPIX - NSIDE) & (NPIX - 1)].x;
            float dhz = z - zl;
            float dvz = z - zu;
            float g21 = 0.0f, g22 = 0.0f;
            if (it != 0) {
                f32x2 bo = gload_f2(bhv + p);         // own addr, L2 hit
                g21 = fmaf(-mu2p, dhz, bo.x);
                g22 = fmaf(-mu2p, dvz, bo.y);
            }
            float ah = dhz - g21 * inv_m2;
            float av = dvz - g22 * inv_m2;
            float uh = copysignf(fmaxf(fabsf(ah) - thr, 0.0f), ah);
            float uv = copysignf(fmaxf(fabsf(av) - thr, 0.0f), av);
            f32x2 bn;
            bn.x = fmaf(mu2, uh, g21);
            bn.y = fmaf(mu2, uv, g22);
            gstore_f2(bhv + p, bn);
        }
        __syncthreads();          // all Z reads done before overwriting C

        // ---- P2: reload (bh,bv) from plane, stage in C for neighbor
        //      exchange (keeps bh/bv out of registers across barriers) ----
        #pragma unroll
        for (int k = 0; k < PXT; ++k) {
            int p = tid + k * NT;
            f32x2 b = gload_f2(bhv + p);
            C[p] = make_float2(b.x, b.y);
        }
        __syncthreads();

        // ---- P3: numerator = a + Dh^T bh + Dv^T bv ----
        float numv[PXT];
        #pragma unroll
        for (int k = 0; k < PXT; ++k) {
            int p    = tid + k * NT;
            int col  = p & (NSIDE - 1);
            int rowb = p & ~(NSIDE - 1);
            float2 own = C[p];
            float bhr = C[rowb | ((col + 1) & (NSIDE - 1))].x;
            float bvd = C[(p + NSIDE) & (NPIX - 1)].y;
            numv[k] = areg[k] + (own.x - bhr) + (own.y - bvd);
        }
        __syncthreads();          // all neighbor reads done before overwrite

        // ---- P4: C <- numerator (real) ----
        #pragma unroll
        for (int k = 0; k < PXT; ++k) {
            int p = tid + k * NT;
            C[p] = make_float2(numv[k], 0.0f);
        }
        __syncthreads();

        // ---- forward FFT over rows (DIF, natural in -> bit-rev out) ----
        for (int s = 0; s < 7; ++s) {
            const int len = 64 >> s;
            #pragma unroll 4
            for (int q = 0; q < 8; ++q) {
                int tau = tid + q * NT;            // 0..8191
                int t   = tau & 63;                // butterfly within row
                int org = (tau >> 6) << 7;         // row * 128
                int j   = t & (len - 1);
                int i0  = ((t ^ j) << 1) | j;
                float2 w = TW[j << s];
                float2 A = C[org + i0];
                float2 B = C[org + i0 + len];
                bfly_fwd(A, B, w.x, w.y);
                C[org + i0]       = A;
                C[org + i0 + len] = B;
            }
            __syncthreads();
        }
        // ---- forward FFT over cols (DIF) ----
        for (int s = 0; s < 7; ++s) {
            const int len = 64 >> s;
            #pragma unroll 4
            for (int q = 0; q < 8; ++q) {
                int tau = tid + q * NT;
                int c   = tau & (NSIDE - 1);
                int t   = tau >> 7;                // 0..63
                int j   = t & (len - 1);
                int i0  = ((t ^ j) << 1) | j;
                int b0  = i0 * NSIDE + c;
                float2 w = TW[j << s];
                float2 A = C[b0];
                float2 B = C[b0 + len * NSIDE];
                bfly_fwd(A, B, w.x, w.y);
                C[b0]               = A;
                C[b0 + len * NSIDE] = B;
            }
            __syncthreads();
        }

        // ---- pointwise Fourier solve (bit-rev indexed), 1/N^2 folded in ----
        {
            const float sc = 1.0f / (float)NPIX;
            #pragma unroll
            for (int k = 0; k < PXT; ++k) {
                int p = tid + k * NT;
                float den = mu1 + mu2 * (D1[p >> 7] + D1[p & (NSIDE - 1)]);
                float f = sc / den;
                float2 v = C[p];
                C[p] = make_float2(v.x * f, v.y * f);
            }
            __syncthreads();
        }

        // ---- inverse FFT over cols (DIT, bit-rev in -> natural out) ----
        for (int s = 0; s < 7; ++s) {
            const int len = 1 << s;
            #pragma unroll 4
            for (int q = 0; q < 8; ++q) {
                int tau = tid + q * NT;
                int c   = tau & (NSIDE - 1);
                int t   = tau >> 7;
                int j   = t & (len - 1);
                int i0  = ((t ^ j) << 1) | j;
                int b0  = i0 * NSIDE + c;
                float2 w = TW[j << (6 - s)];
                float2 A = C[b0];
                float2 B = C[b0 + len * NSIDE];
                bfly_inv(A, B, w.x, w.y);
                C[b0]               = A;
                C[b0 + len * NSIDE] = B;
            }
            __syncthreads();
        }
        // ---- inverse FFT over rows (DIT) ----
        for (int s = 0; s < 7; ++s) {
            const int len = 1 << s;
            #pragma unroll 4
            for (int q = 0; q < 8; ++q) {
                int tau = tid + q * NT;
                int t   = tau & 63;
                int org = (tau >> 6) << 7;
                int j   = t & (len - 1);
                int i0  = ((t ^ j) << 1) | j;
                float2 w = TW[j << (6 - s)];
                float2 A = C[org + i0];
                float2 B = C[org + i0 + len];
                bfly_inv(A, B, w.x, w.y);
                C[org + i0]       = A;
                C[org + i0 + len] = B;
            }
            __syncthreads();
        }

        // ---- Epilogue: X/G1 update; g1 round-trips through the outg plane
        //      (opaque asm); Z stays in C[].x; a stash in C[].y. Last
        //      iteration's plane store becomes the real output (z). ----
        const float mu1n = mu1 * RHO_F;
        const bool  last = (it == N_ITE - 1);
        #pragma unroll
        for (int k = 0; k < PXT; ++k) {
            int p = tid + k * NT;
            float z  = C[p].x;
            float y  = Y[p];
            float w  = Wt[p];
            float g1o = (it == 0) ? 0.0f : gload_f1(g1p + p);
            float x  = fmaf(w, y, fmaf(mu1, z, -g1o)) *
                       __builtin_amdgcn_rcpf(w + mu1);
            float g1n = fmaf(mu1, x - z, g1o);
            gstore_f1(g1p + p, last ? z : g1n);
            ((float*)(C + p))[1] = fmaf(mu1n, x, g1n);   // stash a for next P1
        }
        // no barrier needed: next P1's neighbor reads touch only .x (unchanged
        // since the last FFT barrier); the .y stash is same-thread; P2's
        // overwrites are behind P1's barrier.

        mu1 *= RHO_F;
        mu2 *= RHO_F;
    }
}

extern "C" void kernel_launch(void* const* d_in, const int* in_sizes, int n_in,
                              void* d_out, int out_size, void* d_ws, size_t ws_size,
                              hipStream_t stream) {
    (void)in_sizes; (void)n_in; (void)out_size; (void)ws_size;
    const float* Y   = (const float*)d_in[0];
    const float* inW = (const float*)d_in[1];
    float* out = (float*)d_out;
    f32x2* bhv = (f32x2*)d_ws;    // needs NIMG*NPIX*8 = 16.25 MB (ok in R7)

    hipLaunchKernelGGL(hwtv_kernel, dim3(NIMG), dim3(NT), 0, stream,
                       Y, inW, out, bhv);
}

// Round 7
// 872.791 us; speedup vs baseline: 2.5426x; 2.3991x over previous
//
#include <hip/hip_runtime.h>

// HWTV: ADMM TV solver, 124 independent 128x128 images, 20 iterations.
// One workgroup per image; whole iteration loop in-kernel.
// Round 10: R9's radix-4 fusion with the twiddle-select bug fixed.
// R9 failed correctness (absmax 13.1): the last inverse fused pass (stages
// 5,6) must use wb = TW[j << (5-s)] = TW[j << 0], but was invoked with
// SB=1 (TW[2j] = W_64^j instead of W_128^j). Both INV_*_PASS(1,32) calls
// are now INV_*_PASS(0,32). Everything else identical to R9:
//   - radix-4 fused passes (pairs of radix-2 stages per LDS round-trip),
//     bit-rev permutation and D1 table unchanged.
//   - fwd-col final radix-2 + pointwise solve + inv-col first radix-2
//     fused into one pass.
//   - w2 = w1^2 in-register (halves twiddle LDS reads).
// Per iteration: 29 LDS passes -> 15, barriers 33 -> 19, same FLOPs.
// State (as R3 baseline, best known): a = mu1*X+G1, g1, bh = mu2*Uh+G21,
// bv = mu2*Uv+G22 in per-thread arrays, partial unroll 4.
// FFT: radix-2/4 DIF forward (bit-rev out) -> fused solve with bit-rev
// denom table -> radix-2/4 DIT inverse (bit-rev in). 1/N^2 folded in solve.

#define NPIX   16384
#define NSIDE  128
#define NIMG   124
#define NT     1024
#define PXT    16          // pixels per thread
#define N_ITE  20
#define LAM_F  0.1f
#define RHO_F  1.05f
#define PI_F   3.14159265358979323846f

__device__ __forceinline__ float2 cadd(float2 a, float2 b) {
    return make_float2(a.x + b.x, a.y + b.y);
}
__device__ __forceinline__ float2 csub(float2 a, float2 b) {
    return make_float2(a.x - b.x, a.y - b.y);
}
__device__ __forceinline__ float2 cmul(float2 a, float2 w) {
    return make_float2(fmaf(a.x, w.x, -(a.y * w.y)),
                       fmaf(a.x, w.y,  (a.y * w.x)));
}
__device__ __forceinline__ float2 cmulc(float2 a, float2 w) {   // a * conj(w)
    return make_float2(fmaf(a.x, w.x,  (a.y * w.y)),
                       fmaf(a.y, w.x, -(a.x * w.y)));
}

__global__ __launch_bounds__(NT, 4) void hwtv_kernel(
    const float* __restrict__ Yg,
    const float* __restrict__ Wg,
    float* __restrict__ outg)
{
    extern __shared__ char smem[];
    float2* C  = (float2*)smem;                            // 16384 complex (128 KB)
    float2* TW = (float2*)(smem + (size_t)NPIX * 8);       // 64 twiddles W_128^k
    float*  D1 = (float*)(smem + (size_t)NPIX * 8 + 64*8); // 128: 4sin^2(pi*bitrev7(i)/128)

    const int tid = threadIdx.x;
    const size_t base  = (size_t)blockIdx.x * NPIX;
    const float* Y  = Yg + base;
    const float* Wt = Wg + base;
    float* out = outg + base;

    // ---- one-time tables + Z0 = Y into LDS ----
    if (tid < 64) {
        float ang = -2.0f * PI_F * (float)tid / 128.0f;
        TW[tid] = make_float2(cosf(ang), sinf(ang));
    }
    if (tid < 128) {
        int br = (int)(__brev((unsigned)tid) >> 25);       // bitrev7
        float s = sinf(PI_F * (float)br / 128.0f);
        D1[tid] = 4.0f * s * s;
    }

    // persistent per-thread state (per owned pixel p = tid + k*NT):
    //   a  = mu1*X + G1, g1 = G1,
    //   bh = mu2*Uh + G21 (G21 reconstructed next iter: bh - mu2_prev*DhZ),
    //   bv = mu2*Uv + G22
    float a[PXT], g1[PXT], bh[PXT], bv[PXT];
    #pragma unroll
    for (int k = 0; k < PXT; ++k) {
        int p = tid + k * NT;
        float y = Y[p];
        C[p] = make_float2(y, 0.0f);     // Z0 = Y
        a[k]  = 0.1f * y;                // mu1*X0 + G1_0 = mu1*Y
        g1[k] = 0.0f;
        bh[k] = 0.0f;
        bv[k] = 0.0f;
    }
    __syncthreads();

    float mu1 = 0.1f, mu2 = 0.1f;

    for (int it = 0; it < N_ITE; ++it) {
        const float mu2p   = mu2 * (1.0f / RHO_F);  // previous iteration's mu2
        const float inv_m2 = 1.0f / mu2;
        const float thr    = LAM_F * inv_m2;

        // ---- P1: shrink; bh_new = mu2*Uh + G21, bv_new = mu2*Uv + G22 ----
        #pragma unroll 4
        for (int k = 0; k < PXT; ++k) {
            int p    = tid + k * NT;
            int col  = p & (NSIDE - 1);
            int rowb = p & ~(NSIDE - 1);
            float z  = C[p].x;
            float zl = C[rowb | ((col + NSIDE - 1) & (NSIDE - 1))].x;
            float zu = C[(p + NPIX - NSIDE) & (NPIX - 1)].x;
            float dhz = z - zl;
            float dvz = z - zu;
            float g21 = (it == 0) ? 0.0f : fmaf(-mu2p, dhz, bh[k]);
            float g22 = (it == 0) ? 0.0f : fmaf(-mu2p, dvz, bv[k]);
            float ah = dhz - g21 * inv_m2;
            float av = dvz - g22 * inv_m2;
            float uh = copysignf(fmaxf(fabsf(ah) - thr, 0.0f), ah);
            float uv = copysignf(fmaxf(fabsf(av) - thr, 0.0f), av);
            bh[k] = fmaf(mu2, uh, g21);
            bv[k] = fmaf(mu2, uv, g22);
        }
        __syncthreads();          // all Z reads done before overwriting C

        // ---- P2: stage (bh, bv) in C for neighbor exchange ----
        #pragma unroll 4
        for (int k = 0; k < PXT; ++k) {
            int p = tid + k * NT;
            C[p] = make_float2(bh[k], bv[k]);
        }
        __syncthreads();

        // ---- P3: numerator = a + Dh^T bh + Dv^T bv ----
        float numv[PXT];
        #pragma unroll 4
        for (int k = 0; k < PXT; ++k) {
            int p    = tid + k * NT;
            int col  = p & (NSIDE - 1);
            int rowb = p & ~(NSIDE - 1);
            float bhr = C[rowb | ((col + 1) & (NSIDE - 1))].x;
            float bvd = C[(p + NSIDE) & (NPIX - 1)].y;
            numv[k] = a[k] + (bh[k] - bhr) + (bv[k] - bvd);
        }
        __syncthreads();          // all neighbor reads done before overwrite

        // ---- P4: C <- numerator (real) ----
        #pragma unroll 4
        for (int k = 0; k < PXT; ++k) {
            int p = tid + k * NT;
            C[p] = make_float2(numv[k], 0.0f);
        }
        __syncthreads();

        // ================= forward FFT over rows =================
        // fused radix-4 passes: (s,s+1) for s=0,2,4; L2 = 32>>s
        #define FWD_ROW_PASS(S, L2)                                          \
        {                                                                    \
            _Pragma("unroll 2")                                              \
            for (int q = 0; q < 4; ++q) {                                    \
                int m   = tid + q * NT;                                      \
                int row = m >> 5;                                            \
                int b   = m & 31;                                            \
                int j   = b & ((L2) - 1);                                    \
                int i0  = ((b & ~((L2) - 1)) << 2) | j;                      \
                int p0  = (row << 7) + i0;                                   \
                float2 w1 = TW[j << (S)];                                    \
                float2 w2 = cmul(w1, w1);                                    \
                float2 x0 = C[p0], x1 = C[p0 + (L2)];                        \
                float2 x2 = C[p0 + 2*(L2)], x3 = C[p0 + 3*(L2)];             \
                float2 t02p = cadd(x0, x2);                                  \
                float2 t13p = cadd(x1, x3);                                  \
                float2 t02m = cmul(csub(x0, x2), w1);                        \
                float2 uu   = cmul(csub(x1, x3), w1);                        \
                float2 t13m = make_float2(uu.y, -uu.x);   /* * (-i) */       \
                C[p0]          = cadd(t02p, t13p);                           \
                C[p0 +   (L2)] = cmul(csub(t02p, t13p), w2);                 \
                C[p0 + 2*(L2)] = cadd(t02m, t13m);                           \
                C[p0 + 3*(L2)] = cmul(csub(t02m, t13m), w2);                 \
            }                                                                \
            __syncthreads();                                                 \
        }
        FWD_ROW_PASS(0, 32)
        FWD_ROW_PASS(2, 8)
        FWD_ROW_PASS(4, 2)
        // final radix-2 stage over rows (dist 1, w = 1)
        #pragma unroll 4
        for (int q = 0; q < 8; ++q) {
            int tau = tid + q * NT;
            int t   = tau & 63;
            int org = (tau >> 6) << 7;
            int p0  = org + (t << 1);
            float2 A = C[p0], B = C[p0 + 1];
            C[p0]     = cadd(A, B);
            C[p0 + 1] = csub(A, B);
        }
        __syncthreads();

        // ================= forward FFT over cols (3 fused passes) =========
        #define FWD_COL_PASS(S, L2)                                          \
        {                                                                    \
            _Pragma("unroll 2")                                              \
            for (int q = 0; q < 4; ++q) {                                    \
                int m  = tid + q * NT;                                       \
                int c  = m & 127;                                            \
                int b  = m >> 7;                                             \
                int j  = b & ((L2) - 1);                                     \
                int i0 = ((b & ~((L2) - 1)) << 2) | j;                       \
                int p0 = (i0 << 7) + c;                                      \
                const int ST = (L2) << 7;                                    \
                float2 w1 = TW[j << (S)];                                    \
                float2 w2 = cmul(w1, w1);                                    \
                float2 x0 = C[p0], x1 = C[p0 + ST];                          \
                float2 x2 = C[p0 + 2*ST], x3 = C[p0 + 3*ST];                 \
                float2 t02p = cadd(x0, x2);                                  \
                float2 t13p = cadd(x1, x3);                                  \
                float2 t02m = cmul(csub(x0, x2), w1);                        \
                float2 uu   = cmul(csub(x1, x3), w1);                        \
                float2 t13m = make_float2(uu.y, -uu.x);                      \
                C[p0]        = cadd(t02p, t13p);                             \
                C[p0 +   ST] = cmul(csub(t02p, t13p), w2);                   \
                C[p0 + 2*ST] = cadd(t02m, t13m);                             \
                C[p0 + 3*ST] = cmul(csub(t02m, t13m), w2);                   \
            }                                                                \
            __syncthreads();                                                 \
        }
        FWD_COL_PASS(0, 32)
        FWD_COL_PASS(2, 8)
        FWD_COL_PASS(4, 2)

        // ==== fused: fwd-col radix-2 (dist 1) + solve + inv-col radix-2 ====
        {
            const float sc = 1.0f / (float)NPIX;
            #pragma unroll 4
            for (int q = 0; q < 8; ++q) {
                int tau = tid + q * NT;
                int c   = tau & 127;
                int t   = tau >> 7;          // 0..63
                int r0  = t << 1;
                int p0  = (r0 << 7) + c;
                float2 A = C[p0], B = C[p0 + NSIDE];
                float2 s2 = cadd(A, B);      // -> spectral row r0
                float2 d2 = csub(A, B);      // -> spectral row r0+1
                float d1c = D1[c];
                float f0 = sc / fmaf(mu2, D1[r0]     + d1c, mu1);
                float f1 = sc / fmaf(mu2, D1[r0 + 1] + d1c, mu1);
                s2.x *= f0; s2.y *= f0;
                d2.x *= f1; d2.y *= f1;
                C[p0]         = cadd(s2, d2);   // inv radix-2 (w = 1)
                C[p0 + NSIDE] = csub(s2, d2);
            }
            __syncthreads();
        }

        // ================= inverse FFT over cols (3 fused passes) =========
        // fused DIT pairs (s,s+1) for s=1,3,5; M = 1<<s; wb = TW[j<<(5-s)]
        #define INV_COL_PASS(SB, M)                                          \
        {                                                                    \
            _Pragma("unroll 2")                                              \
            for (int q = 0; q < 4; ++q) {                                    \
                int m  = tid + q * NT;                                       \
                int c  = m & 127;                                            \
                int b  = m >> 7;                                             \
                int j  = b & ((M) - 1);                                      \
                int i0 = ((b & ~((M) - 1)) << 2) | j;                        \
                int p0 = (i0 << 7) + c;                                      \
                const int ST = (M) << 7;                                     \
                float2 wb = TW[j << (SB)];                                   \
                float2 wa = cmul(wb, wb);                                    \
                float2 x0 = C[p0], x1 = C[p0 + ST];                          \
                float2 x2 = C[p0 + 2*ST], x3 = C[p0 + 3*ST];                 \
                float2 pp1 = cmulc(x1, wa);                                  \
                float2 a0 = cadd(x0, pp1), a1 = csub(x0, pp1);               \
                float2 pp2 = cmulc(x3, wa);                                  \
                float2 a2 = cadd(x2, pp2), a3 = csub(x2, pp2);               \
                float2 q0 = cmulc(a2, wb);                                   \
                float2 y0 = cadd(a0, q0), y2 = csub(a0, q0);                 \
                float2 uu = cmulc(a3, wb);                                   \
                float2 q1 = make_float2(-uu.y, uu.x);     /* * (+i) */       \
                float2 y1 = cadd(a1, q1), y3 = csub(a1, q1);                 \
                C[p0]        = y0;                                           \
                C[p0 +   ST] = y1;                                           \
                C[p0 + 2*ST] = y2;                                           \
                C[p0 + 3*ST] = y3;                                           \
            }                                                                \
            __syncthreads();                                                 \
        }
        INV_COL_PASS(4, 2)
        INV_COL_PASS(2, 8)
        INV_COL_PASS(0, 32)   // R9 BUG WAS HERE: SB must be 5-s = 0 for s=5

        // ================= inverse FFT over rows =================
        // radix-2 first (dist 1, w = 1)
        #pragma unroll 4
        for (int q = 0; q < 8; ++q) {
            int tau = tid + q * NT;
            int t   = tau & 63;
            int org = (tau >> 6) << 7;
            int p0  = org + (t << 1);
            float2 A = C[p0], B = C[p0 + 1];
            C[p0]     = cadd(A, B);
            C[p0 + 1] = csub(A, B);
        }
        __syncthreads();
        #define INV_ROW_PASS(SB, M)                                          \
        {                                                                    \
            _Pragma("unroll 2")                                              \
            for (int q = 0; q < 4; ++q) {                                    \
                int m   = tid + q * NT;                                      \
                int row = m >> 5;                                            \
                int b   = m & 31;                                            \
                int j   = b & ((M) - 1);                                     \
                int i0  = ((b & ~((M) - 1)) << 2) | j;                       \
                int p0  = (row << 7) + i0;                                   \
                float2 wb = TW[j << (SB)];                                   \
                float2 wa = cmul(wb, wb);                                    \
                float2 x0 = C[p0], x1 = C[p0 + (M)];                         \
                float2 x2 = C[p0 + 2*(M)], x3 = C[p0 + 3*(M)];               \
                float2 pp1 = cmulc(x1, wa);                                  \
                float2 a0 = cadd(x0, pp1), a1 = csub(x0, pp1);               \
                float2 pp2 = cmulc(x3, wa);                                  \
                float2 a2 = cadd(x2, pp2), a3 = csub(x2, pp2);               \
                float2 q0 = cmulc(a2, wb);                                   \
                float2 y0 = cadd(a0, q0), y2 = csub(a0, q0);                 \
                float2 uu = cmulc(a3, wb);                                   \
                float2 q1 = make_float2(-uu.y, uu.x);                        \
                float2 y1 = cadd(a1, q1), y3 = csub(a1, q1);                 \
                C[p0]         = y0;                                          \
                C[p0 +   (M)] = y1;                                          \
                C[p0 + 2*(M)] = y2;                                          \
                C[p0 + 3*(M)] = y3;                                          \
            }                                                                \
            __syncthreads();                                                 \
        }
        INV_ROW_PASS(4, 2)
        INV_ROW_PASS(2, 8)
        INV_ROW_PASS(0, 32)   // R9 BUG WAS HERE TOO: SB = 0, not 1

        // ---- Epilogue: X/G1/a update in registers; Z stays in C[].x ----
        const float mu1n = mu1 * RHO_F;
        #pragma unroll 4
        for (int k = 0; k < PXT; ++k) {
            int p = tid + k * NT;
            float z  = C[p].x;
            float y  = Y[p];
            float w  = Wt[p];
            float x  = fmaf(w, y, fmaf(mu1, z, -g1[k])) *
                       __builtin_amdgcn_rcpf(w + mu1);
            g1[k] = fmaf(mu1, x - z, g1[k]);
            a[k]  = fmaf(mu1n, x, g1[k]);
            if (it == N_ITE - 1) out[p] = z;
        }
        // no barrier needed: next P1 only reads C (covered by the FFT's last
        // barrier); P2's writes are behind P1's barrier.

        mu1 *= RHO_F;
        mu2 *= RHO_F;
    }
}

extern "C" void kernel_launch(void* const* d_in, const int* in_sizes, int n_in,
                              void* d_out, int out_size, void* d_ws, size_t ws_size,
                              hipStream_t stream) {
    (void)in_sizes; (void)n_in; (void)out_size; (void)d_ws; (void)ws_size;
    const float* Y   = (const float*)d_in[0];
    const float* inW = (const float*)d_in[1];
    float* out = (float*)d_out;

    const size_t smem_bytes = (size_t)NPIX * 8 + 64 * 8 + 128 * 4;  // 132096
    hipFuncSetAttribute((const void*)hwtv_kernel,
                        hipFuncAttributeMaxDynamicSharedMemorySize,
                        (int)smem_bytes);
    hipLaunchKernelGGL(hwtv_kernel, dim3(NIMG), dim3(NT), smem_bytes, stream,
                       Y, inW, out);
}

// Round 8
// 779.045 us; speedup vs baseline: 2.8486x; 1.1203x over previous
//
#include <hip/hip_runtime.h>

// HWTV: ADMM TV solver, 124 independent 128x128 images, 20 iterations.
// One workgroup per image; whole iteration loop in-kernel.
// Round 11: R10 (radix-4 fused FFT, 872us) + LDS bank swizzle.
// R10's counters showed SQ_LDS_BANK_CONFLICT UP vs radix-2 (6.6e7 cyc ~=
// 220us/block-serial): the radix-4 row passes fix column bits by access
// index (L2=8: bits {3,4} fixed -> 4-way; L2=2: bits {1,2} fixed -> 8-way;
// stride-1 radix-2: bit 0 fixed, one row across 64 lanes -> 8-way).
// Fix: physical column swizzle phys = col ^ (col>>3). Bank bits become
// (c0^c3, c1^c4, c2^c5, c3^c6); every row-pass access set now has all four
// free -> conflict-free. Col passes keep col fixed per access (row stride
// == 0 mod 32 banks) and consecutive-c lanes stay balanced (bijective map).
// Same arithmetic, same values, different LDS slots -- numerics identical.
// Everything else identical to R10.

#define NPIX   16384
#define NSIDE  128
#define NIMG   124
#define NT     1024
#define PXT    16          // pixels per thread
#define N_ITE  20
#define LAM_F  0.1f
#define RHO_F  1.05f
#define PI_F   3.14159265358979323846f

// physical column swizzle: spreads FFT strided row-access sets across banks
#define SW(c) ((c) ^ ((c) >> 3))

__device__ __forceinline__ float2 cadd(float2 a, float2 b) {
    return make_float2(a.x + b.x, a.y + b.y);
}
__device__ __forceinline__ float2 csub(float2 a, float2 b) {
    return make_float2(a.x - b.x, a.y - b.y);
}
__device__ __forceinline__ float2 cmul(float2 a, float2 w) {
    return make_float2(fmaf(a.x, w.x, -(a.y * w.y)),
                       fmaf(a.x, w.y,  (a.y * w.x)));
}
__device__ __forceinline__ float2 cmulc(float2 a, float2 w) {   // a * conj(w)
    return make_float2(fmaf(a.x, w.x,  (a.y * w.y)),
                       fmaf(a.y, w.x, -(a.x * w.y)));
}

__global__ __launch_bounds__(NT, 4) void hwtv_kernel(
    const float* __restrict__ Yg,
    const float* __restrict__ Wg,
    float* __restrict__ outg)
{
    extern __shared__ char smem[];
    float2* C  = (float2*)smem;                            // 16384 complex (128 KB)
    float2* TW = (float2*)(smem + (size_t)NPIX * 8);       // 64 twiddles W_128^k
    float*  D1 = (float*)(smem + (size_t)NPIX * 8 + 64*8); // 128: 4sin^2(pi*bitrev7(i)/128)

    const int tid = threadIdx.x;
    const size_t base  = (size_t)blockIdx.x * NPIX;
    const float* Y  = Yg + base;
    const float* Wt = Wg + base;
    float* out = outg + base;

    // ---- one-time tables + Z0 = Y into LDS ----
    if (tid < 64) {
        float ang = -2.0f * PI_F * (float)tid / 128.0f;
        TW[tid] = make_float2(cosf(ang), sinf(ang));
    }
    if (tid < 128) {
        int br = (int)(__brev((unsigned)tid) >> 25);       // bitrev7
        float s = sinf(PI_F * (float)br / 128.0f);
        D1[tid] = 4.0f * s * s;
    }

    // persistent per-thread state (per owned pixel p = tid + k*NT):
    //   a  = mu1*X + G1, g1 = G1,
    //   bh = mu2*Uh + G21 (G21 reconstructed next iter: bh - mu2_prev*DhZ),
    //   bv = mu2*Uv + G22
    float a[PXT], g1[PXT], bh[PXT], bv[PXT];
    #pragma unroll
    for (int k = 0; k < PXT; ++k) {
        int p = tid + k * NT;
        int col = p & (NSIDE - 1);
        int rowb = p & ~(NSIDE - 1);
        float y = Y[p];
        C[rowb + SW(col)] = make_float2(y, 0.0f);   // Z0 = Y
        a[k]  = 0.1f * y;                // mu1*X0 + G1_0 = mu1*Y
        g1[k] = 0.0f;
        bh[k] = 0.0f;
        bv[k] = 0.0f;
    }
    __syncthreads();

    float mu1 = 0.1f, mu2 = 0.1f;

    for (int it = 0; it < N_ITE; ++it) {
        const float mu2p   = mu2 * (1.0f / RHO_F);  // previous iteration's mu2
        const float inv_m2 = 1.0f / mu2;
        const float thr    = LAM_F * inv_m2;

        // ---- P1: shrink; bh_new = mu2*Uh + G21, bv_new = mu2*Uv + G22 ----
        #pragma unroll 4
        for (int k = 0; k < PXT; ++k) {
            int p    = tid + k * NT;
            int col  = p & (NSIDE - 1);
            int rowb = p & ~(NSIDE - 1);
            int sc_  = SW(col);
            float z  = C[rowb + sc_].x;
            float zl = C[rowb + SW((col + NSIDE - 1) & (NSIDE - 1))].x;
            int pu   = (p + NPIX - NSIDE) & (NPIX - 1);
            float zu = C[(pu & ~(NSIDE - 1)) + sc_].x;
            float dhz = z - zl;
            float dvz = z - zu;
            float g21 = (it == 0) ? 0.0f : fmaf(-mu2p, dhz, bh[k]);
            float g22 = (it == 0) ? 0.0f : fmaf(-mu2p, dvz, bv[k]);
            float ah = dhz - g21 * inv_m2;
            float av = dvz - g22 * inv_m2;
            float uh = copysignf(fmaxf(fabsf(ah) - thr, 0.0f), ah);
            float uv = copysignf(fmaxf(fabsf(av) - thr, 0.0f), av);
            bh[k] = fmaf(mu2, uh, g21);
            bv[k] = fmaf(mu2, uv, g22);
        }
        __syncthreads();          // all Z reads done before overwriting C

        // ---- P2: stage (bh, bv) in C for neighbor exchange ----
        #pragma unroll 4
        for (int k = 0; k < PXT; ++k) {
            int p = tid + k * NT;
            int col = p & (NSIDE - 1);
            int rowb = p & ~(NSIDE - 1);
            C[rowb + SW(col)] = make_float2(bh[k], bv[k]);
        }
        __syncthreads();

        // ---- P3: numerator = a + Dh^T bh + Dv^T bv ----
        float numv[PXT];
        #pragma unroll 4
        for (int k = 0; k < PXT; ++k) {
            int p    = tid + k * NT;
            int col  = p & (NSIDE - 1);
            int rowb = p & ~(NSIDE - 1);
            int sc_  = SW(col);
            float bhr = C[rowb + SW((col + 1) & (NSIDE - 1))].x;
            int pd    = (p + NSIDE) & (NPIX - 1);
            float bvd = C[(pd & ~(NSIDE - 1)) + sc_].y;
            numv[k] = a[k] + (bh[k] - bhr) + (bv[k] - bvd);
        }
        __syncthreads();          // all neighbor reads done before overwrite

        // ---- P4: C <- numerator (real) ----
        #pragma unroll 4
        for (int k = 0; k < PXT; ++k) {
            int p = tid + k * NT;
            int col = p & (NSIDE - 1);
            int rowb = p & ~(NSIDE - 1);
            C[rowb + SW(col)] = make_float2(numv[k], 0.0f);
        }
        __syncthreads();

        // ================= forward FFT over rows =================
        // fused radix-4 passes: (s,s+1) for s=0,2,4; L2 = 32>>s
        #define FWD_ROW_PASS(S, L2)                                          \
        {                                                                    \
            _Pragma("unroll 2")                                              \
            for (int q = 0; q < 4; ++q) {                                    \
                int m   = tid + q * NT;                                      \
                int rb  = (m >> 5) << 7;                                     \
                int b   = m & 31;                                            \
                int j   = b & ((L2) - 1);                                    \
                int i0  = ((b & ~((L2) - 1)) << 2) | j;                      \
                int e0 = rb + SW(i0);                                        \
                int e1 = rb + SW(i0 + (L2));                                 \
                int e2 = rb + SW(i0 + 2*(L2));                               \
                int e3 = rb + SW(i0 + 3*(L2));                               \
                float2 w1 = TW[j << (S)];                                    \
                float2 w2 = cmul(w1, w1);                                    \
                float2 x0 = C[e0], x1 = C[e1];                               \
                float2 x2 = C[e2], x3 = C[e3];                               \
                float2 t02p = cadd(x0, x2);                                  \
                float2 t13p = cadd(x1, x3);                                  \
                float2 t02m = cmul(csub(x0, x2), w1);                        \
                float2 uu   = cmul(csub(x1, x3), w1);                        \
                float2 t13m = make_float2(uu.y, -uu.x);   /* * (-i) */       \
                C[e0] = cadd(t02p, t13p);                                    \
                C[e1] = cmul(csub(t02p, t13p), w2);                          \
                C[e2] = cadd(t02m, t13m);                                    \
                C[e3] = cmul(csub(t02m, t13m), w2);                          \
            }                                                                \
            __syncthreads();                                                 \
        }
        FWD_ROW_PASS(0, 32)
        FWD_ROW_PASS(2, 8)
        FWD_ROW_PASS(4, 2)
        // final radix-2 stage over rows (dist 1, w = 1)
        #pragma unroll 4
        for (int q = 0; q < 8; ++q) {
            int tau = tid + q * NT;
            int t   = tau & 63;
            int org = (tau >> 6) << 7;
            int c0  = t << 1;
            int ea  = org + SW(c0);
            int eb  = org + SW(c0 + 1);
            float2 A = C[ea], B = C[eb];
            C[ea] = cadd(A, B);
            C[eb] = csub(A, B);
        }
        __syncthreads();

        // ================= forward FFT over cols (3 fused passes) =========
        #define FWD_COL_PASS(S, L2)                                          \
        {                                                                    \
            _Pragma("unroll 2")                                              \
            for (int q = 0; q < 4; ++q) {                                    \
                int m  = tid + q * NT;                                       \
                int c  = m & 127;                                            \
                int b  = m >> 7;                                             \
                int j  = b & ((L2) - 1);                                     \
                int i0 = ((b & ~((L2) - 1)) << 2) | j;                       \
                int p0 = (i0 << 7) + SW(c);                                  \
                const int ST = (L2) << 7;                                    \
                float2 w1 = TW[j << (S)];                                    \
                float2 w2 = cmul(w1, w1);                                    \
                float2 x0 = C[p0], x1 = C[p0 + ST];                          \
                float2 x2 = C[p0 + 2*ST], x3 = C[p0 + 3*ST];                 \
                float2 t02p = cadd(x0, x2);                                  \
                float2 t13p = cadd(x1, x3);                                  \
                float2 t02m = cmul(csub(x0, x2), w1);                        \
                float2 uu   = cmul(csub(x1, x3), w1);                        \
                float2 t13m = make_float2(uu.y, -uu.x);                      \
                C[p0]        = cadd(t02p, t13p);                             \
                C[p0 +   ST] = cmul(csub(t02p, t13p), w2);                   \
                C[p0 + 2*ST] = cadd(t02m, t13m);                             \
                C[p0 + 3*ST] = cmul(csub(t02m, t13m), w2);                   \
            }                                                                \
            __syncthreads();                                                 \
        }
        FWD_COL_PASS(0, 32)
        FWD_COL_PASS(2, 8)
        FWD_COL_PASS(4, 2)

        // ==== fused: fwd-col radix-2 (dist 1) + solve + inv-col radix-2 ====
        {
            const float sc = 1.0f / (float)NPIX;
            #pragma unroll 4
            for (int q = 0; q < 8; ++q) {
                int tau = tid + q * NT;
                int c   = tau & 127;
                int t   = tau >> 7;          // 0..63
                int r0  = t << 1;
                int p0  = (r0 << 7) + SW(c);
                float2 A = C[p0], B = C[p0 + NSIDE];
                float2 s2 = cadd(A, B);      // -> spectral row r0
                float2 d2 = csub(A, B);      // -> spectral row r0+1
                float d1c = D1[c];
                float f0 = sc / fmaf(mu2, D1[r0]     + d1c, mu1);
                float f1 = sc / fmaf(mu2, D1[r0 + 1] + d1c, mu1);
                s2.x *= f0; s2.y *= f0;
                d2.x *= f1; d2.y *= f1;
                C[p0]         = cadd(s2, d2);   // inv radix-2 (w = 1)
                C[p0 + NSIDE] = csub(s2, d2);
            }
            __syncthreads();
        }

        // ================= inverse FFT over cols (3 fused passes) =========
        // fused DIT pairs (s,s+1) for s=1,3,5; M = 1<<s; wb = TW[j<<(5-s)]
        #define INV_COL_PASS(SB, M)                                          \
        {                                                                    \
            _Pragma("unroll 2")                                              \
            for (int q = 0; q < 4; ++q) {                                    \
                int m  = tid + q * NT;                                       \
                int c  = m & 127;                                            \
                int b  = m >> 7;                                             \
                int j  = b & ((M) - 1);                                      \
                int i0 = ((b & ~((M) - 1)) << 2) | j;                        \
                int p0 = (i0 << 7) + SW(c);                                  \
                const int ST = (M) << 7;                                     \
                float2 wb = TW[j << (SB)];                                   \
                float2 wa = cmul(wb, wb);                                    \
                float2 x0 = C[p0], x1 = C[p0 + ST];                          \
                float2 x2 = C[p0 + 2*ST], x3 = C[p0 + 3*ST];                 \
                float2 pp1 = cmulc(x1, wa);                                  \
                float2 a0 = cadd(x0, pp1), a1 = csub(x0, pp1);               \
                float2 pp2 = cmulc(x3, wa);                                  \
                float2 a2 = cadd(x2, pp2), a3 = csub(x2, pp2);               \
                float2 q0 = cmulc(a2, wb);                                   \
                float2 y0 = cadd(a0, q0), y2 = csub(a0, q0);                 \
                float2 uu = cmulc(a3, wb);                                   \
                float2 q1 = make_float2(-uu.y, uu.x);     /* * (+i) */       \
                float2 y1 = cadd(a1, q1), y3 = csub(a1, q1);                 \
                C[p0]        = y0;                                           \
                C[p0 +   ST] = y1;                                           \
                C[p0 + 2*ST] = y2;                                           \
                C[p0 + 3*ST] = y3;                                           \
            }                                                                \
            __syncthreads();                                                 \
        }
        INV_COL_PASS(4, 2)
        INV_COL_PASS(2, 8)
        INV_COL_PASS(0, 32)

        // ================= inverse FFT over rows =================
        // radix-2 first (dist 1, w = 1)
        #pragma unroll 4
        for (int q = 0; q < 8; ++q) {
            int tau = tid + q * NT;
            int t   = tau & 63;
            int org = (tau >> 6) << 7;
            int c0  = t << 1;
            int ea  = org + SW(c0);
            int eb  = org + SW(c0 + 1);
            float2 A = C[ea], B = C[eb];
            C[ea] = cadd(A, B);
            C[eb] = csub(A, B);
        }
        __syncthreads();
        #define INV_ROW_PASS(SB, M)                                          \
        {                                                                    \
            _Pragma("unroll 2")                                              \
            for (int q = 0; q < 4; ++q) {                                    \
                int m   = tid + q * NT;                                      \
                int rb  = (m >> 5) << 7;                                     \
                int b   = m & 31;                                            \
                int j   = b & ((M) - 1);                                     \
                int i0  = ((b & ~((M) - 1)) << 2) | j;                       \
                int e0 = rb + SW(i0);                                        \
                int e1 = rb + SW(i0 + (M));                                  \
                int e2 = rb + SW(i0 + 2*(M));                                \
                int e3 = rb + SW(i0 + 3*(M));                                \
                float2 wb = TW[j << (SB)];                                   \
                float2 wa = cmul(wb, wb);                                    \
                float2 x0 = C[e0], x1 = C[e1];                               \
                float2 x2 = C[e2], x3 = C[e3];                               \
                float2 pp1 = cmulc(x1, wa);                                  \
                float2 a0 = cadd(x0, pp1), a1 = csub(x0, pp1);               \
                float2 pp2 = cmulc(x3, wa);                                  \
                float2 a2 = cadd(x2, pp2), a3 = csub(x2, pp2);               \
                float2 q0 = cmulc(a2, wb);                                   \
                float2 y0 = cadd(a0, q0), y2 = csub(a0, q0);                 \
                float2 uu = cmulc(a3, wb);                                   \
                float2 q1 = make_float2(-uu.y, uu.x);                        \
                float2 y1 = cadd(a1, q1), y3 = csub(a1, q1);                 \
                C[e0] = y0;                                                  \
                C[e1] = y1;                                                  \
                C[e2] = y2;                                                  \
                C[e3] = y3;                                                  \
            }                                                                \
            __syncthreads();                                                 \
        }
        INV_ROW_PASS(4, 2)
        INV_ROW_PASS(2, 8)
        INV_ROW_PASS(0, 32)

        // ---- Epilogue: X/G1/a update in registers; Z stays in C[].x ----
        const float mu1n = mu1 * RHO_F;
        #pragma unroll 4
        for (int k = 0; k < PXT; ++k) {
            int p = tid + k * NT;
            int col = p & (NSIDE - 1);
            int rowb = p & ~(NSIDE - 1);
            float z  = C[rowb + SW(col)].x;
            float y  = Y[p];
            float w  = Wt[p];
            float x  = fmaf(w, y, fmaf(mu1, z, -g1[k])) *
                       __builtin_amdgcn_rcpf(w + mu1);
            g1[k] = fmaf(mu1, x - z, g1[k]);
            a[k]  = fmaf(mu1n, x, g1[k]);
            if (it == N_ITE - 1) out[p] = z;
        }
        // no barrier needed: next P1 only reads C (covered by the FFT's last
        // barrier); P2's writes are behind P1's barrier.

        mu1 *= RHO_F;
        mu2 *= RHO_F;
    }
}

extern "C" void kernel_launch(void* const* d_in, const int* in_sizes, int n_in,
                              void* d_out, int out_size, void* d_ws, size_t ws_size,
                              hipStream_t stream) {
    (void)in_sizes; (void)n_in; (void)out_size; (void)d_ws; (void)ws_size;
    const float* Y   = (const float*)d_in[0];
    const float* inW = (const float*)d_in[1];
    float* out = (float*)d_out;

    const size_t smem_bytes = (size_t)NPIX * 8 + 64 * 8 + 128 * 4;  // 132096
    hipFuncSetAttribute((const void*)hwtv_kernel,
                        hipFuncAttributeMaxDynamicSharedMemorySize,
                        (int)smem_bytes);
    hipLaunchKernelGGL(hwtv_kernel, dim3(NIMG), dim3(NT), smem_bytes, stream,
                       Y, inW, out);
}

// Round 9
// 660.826 us; speedup vs baseline: 3.3582x; 1.1789x over previous
//
#include <hip/hip_runtime.h>

// HWTV: ADMM TV solver, 124 independent 128x128 images, 20 iterations.
// One workgroup per image; whole iteration loop in-kernel.
// Round 12: radix-8 fusions on top of R11 (779us). LDS-pass accounting says
// the LDS pipe is ~57% of runtime -> cut passes. The distance<=4 FFT stages
// live inside aligned 8-element groups with COMPILE-TIME twiddles (W8/W4
// powers), so:
//   - rows fwd:  radix4(4,2) + stride-1 radix2  -> one radix-8 pass
//   - rows inv:  stride-1 radix2 + radix4(4,2)  -> one inverse radix-8 pass
//   - cols:      radix4(4,2) + [r2+solve+r2] + inv radix4(4,2)
//                -> ONE mega-pass (fwd radix-8 + solve x8 + inv radix-8)
// FFT passes 15 -> 11, barriers 19 -> 15; the new passes load no twiddles.
// Derived by composing the verified R10/R11 radix-2 stage algebra; stage
// coverage: rows 0,1|2,3|4,5,6 ; cols 0,1|2,3|{456+solve+012}|3,4|5,6.
// Arithmetic identical (fusion removes exact float LDS round-trips).
// Bank check (new passes): 8-consecutive groups map bijectively onto 16
// bank-pairs (4 lanes each = b64 optimum) under SW; col mega reads 64
// consecutive swizzled cols per row -> optimal. SW(c)=c^(c>>3) as R11.

#define NPIX   16384
#define NSIDE  128
#define NIMG   124
#define NT     1024
#define PXT    16          // pixels per thread
#define N_ITE  20
#define LAM_F  0.1f
#define RHO_F  1.05f
#define PI_F   3.14159265358979323846f

// physical column swizzle: spreads FFT strided row-access sets across banks
#define SW(c) ((c) ^ ((c) >> 3))

__device__ __forceinline__ float2 cadd(float2 a, float2 b) {
    return make_float2(a.x + b.x, a.y + b.y);
}
__device__ __forceinline__ float2 csub(float2 a, float2 b) {
    return make_float2(a.x - b.x, a.y - b.y);
}
__device__ __forceinline__ float2 cmul(float2 a, float2 w) {
    return make_float2(fmaf(a.x, w.x, -(a.y * w.y)),
                       fmaf(a.x, w.y,  (a.y * w.x)));
}
__device__ __forceinline__ float2 cmulc(float2 a, float2 w) {   // a * conj(w)
    return make_float2(fmaf(a.x, w.x,  (a.y * w.y)),
                       fmaf(a.y, w.x, -(a.x * w.y)));
}

#define RT2H 0.70710678118654752f   // sqrt(2)/2

// forward radix-8 (DIF stages len=4,2,1) on 8 consecutive elements.
// twiddles: stage4 W8^j (j=p&3), stage5 W4^(p&1), stage6 1 -- all constant.
__device__ __forceinline__ void radix8_fwd(float2 z[8]) {
    float2 A0 = cadd(z[0], z[4]), A1 = cadd(z[1], z[5]);
    float2 A2 = cadd(z[2], z[6]), A3 = cadd(z[3], z[7]);
    float2 d0 = csub(z[0], z[4]), d1 = csub(z[1], z[5]);
    float2 d2 = csub(z[2], z[6]), d3 = csub(z[3], z[7]);
    float2 B0 = d0;                                            // *W8^0
    float2 B1 = make_float2(RT2H*(d1.x + d1.y), RT2H*(d1.y - d1.x)); // *(c,-c)
    float2 B2 = make_float2(d2.y, -d2.x);                      // *(-i)
    float2 B3 = make_float2(RT2H*(d3.y - d3.x), -RT2H*(d3.x + d3.y)); // *(-c,-c)
    float2 C0 = cadd(A0, A2), C2 = csub(A0, A2);
    float2 t13 = csub(A1, A3);
    float2 C1 = cadd(A1, A3);
    float2 C3 = make_float2(t13.y, -t13.x);                    // *(-i)
    float2 E0 = cadd(B0, B2), E2 = csub(B0, B2);
    float2 u13 = csub(B1, B3);
    float2 E1 = cadd(B1, B3);
    float2 E3 = make_float2(u13.y, -u13.x);
    z[0] = cadd(C0, C1);  z[1] = csub(C0, C1);
    z[2] = cadd(C2, C3);  z[3] = csub(C2, C3);
    z[4] = cadd(E0, E1);  z[5] = csub(E0, E1);
    z[6] = cadd(E2, E3);  z[7] = csub(E2, E3);
}

// inverse radix-8 (DIT stages len=1,2,4) on 8 consecutive elements.
// twiddles: stage1 conj(W4)^(p&1)=+i, stage2 conj(W8^j) -- all constant.
__device__ __forceinline__ void radix8_inv(float2 z[8]) {
    float2 a0 = cadd(z[0], z[1]), a1 = csub(z[0], z[1]);
    float2 a2 = cadd(z[2], z[3]), a3 = csub(z[2], z[3]);
    float2 a4 = cadd(z[4], z[5]), a5 = csub(z[4], z[5]);
    float2 a6 = cadd(z[6], z[7]), a7 = csub(z[6], z[7]);
    float2 b0 = cadd(a0, a2), b2 = csub(a0, a2);
    float2 t3 = make_float2(-a3.y, a3.x);                      // a3 * (+i)
    float2 b1 = cadd(a1, t3), b3 = csub(a1, t3);
    float2 b4 = cadd(a4, a6), b6 = csub(a4, a6);
    float2 t7 = make_float2(-a7.y, a7.x);
    float2 b5 = cadd(a5, t7), b7 = csub(a5, t7);
    float2 p0 = b4;                                            // *conj(W8^0)
    float2 p1 = make_float2(RT2H*(b5.x - b5.y), RT2H*(b5.x + b5.y)); // *(c,c)
    float2 p2 = make_float2(-b6.y, b6.x);                      // *(+i)
    float2 p3 = make_float2(-RT2H*(b7.x + b7.y), RT2H*(b7.x - b7.y)); // *(-c,c)
    z[0] = cadd(b0, p0);  z[4] = csub(b0, p0);
    z[1] = cadd(b1, p1);  z[5] = csub(b1, p1);
    z[2] = cadd(b2, p2);  z[6] = csub(b2, p2);
    z[3] = cadd(b3, p3);  z[7] = csub(b3, p3);
}

__global__ __launch_bounds__(NT, 4) void hwtv_kernel(
    const float* __restrict__ Yg,
    const float* __restrict__ Wg,
    float* __restrict__ outg)
{
    extern __shared__ char smem[];
    float2* C  = (float2*)smem;                            // 16384 complex (128 KB)
    float2* TW = (float2*)(smem + (size_t)NPIX * 8);       // 64 twiddles W_128^k
    float*  D1 = (float*)(smem + (size_t)NPIX * 8 + 64*8); // 128: 4sin^2(pi*bitrev7(i)/128)

    const int tid = threadIdx.x;
    const size_t base  = (size_t)blockIdx.x * NPIX;
    const float* Y  = Yg + base;
    const float* Wt = Wg + base;
    float* out = outg + base;

    // ---- one-time tables + Z0 = Y into LDS ----
    if (tid < 64) {
        float ang = -2.0f * PI_F * (float)tid / 128.0f;
        TW[tid] = make_float2(cosf(ang), sinf(ang));
    }
    if (tid < 128) {
        int br = (int)(__brev((unsigned)tid) >> 25);       // bitrev7
        float s = sinf(PI_F * (float)br / 128.0f);
        D1[tid] = 4.0f * s * s;
    }

    float a[PXT], g1[PXT], bh[PXT], bv[PXT];
    #pragma unroll
    for (int k = 0; k < PXT; ++k) {
        int p = tid + k * NT;
        int col = p & (NSIDE - 1);
        int rowb = p & ~(NSIDE - 1);
        float y = Y[p];
        C[rowb + SW(col)] = make_float2(y, 0.0f);   // Z0 = Y
        a[k]  = 0.1f * y;                // mu1*X0 + G1_0 = mu1*Y
        g1[k] = 0.0f;
        bh[k] = 0.0f;
        bv[k] = 0.0f;
    }
    __syncthreads();

    float mu1 = 0.1f, mu2 = 0.1f;

    for (int it = 0; it < N_ITE; ++it) {
        const float mu2p   = mu2 * (1.0f / RHO_F);  // previous iteration's mu2
        const float inv_m2 = 1.0f / mu2;
        const float thr    = LAM_F * inv_m2;

        // ---- P1: shrink; bh_new = mu2*Uh + G21, bv_new = mu2*Uv + G22 ----
        #pragma unroll 4
        for (int k = 0; k < PXT; ++k) {
            int p    = tid + k * NT;
            int col  = p & (NSIDE - 1);
            int rowb = p & ~(NSIDE - 1);
            int sc_  = SW(col);
            float z  = C[rowb + sc_].x;
            float zl = C[rowb + SW((col + NSIDE - 1) & (NSIDE - 1))].x;
            int pu   = (p + NPIX - NSIDE) & (NPIX - 1);
            float zu = C[(pu & ~(NSIDE - 1)) + sc_].x;
            float dhz = z - zl;
            float dvz = z - zu;
            float g21 = (it == 0) ? 0.0f : fmaf(-mu2p, dhz, bh[k]);
            float g22 = (it == 0) ? 0.0f : fmaf(-mu2p, dvz, bv[k]);
            float ah = dhz - g21 * inv_m2;
            float av = dvz - g22 * inv_m2;
            float uh = copysignf(fmaxf(fabsf(ah) - thr, 0.0f), ah);
            float uv = copysignf(fmaxf(fabsf(av) - thr, 0.0f), av);
            bh[k] = fmaf(mu2, uh, g21);
            bv[k] = fmaf(mu2, uv, g22);
        }
        __syncthreads();          // all Z reads done before overwriting C

        // ---- P2: stage (bh, bv) in C for neighbor exchange ----
        #pragma unroll 4
        for (int k = 0; k < PXT; ++k) {
            int p = tid + k * NT;
            int col = p & (NSIDE - 1);
            int rowb = p & ~(NSIDE - 1);
            C[rowb + SW(col)] = make_float2(bh[k], bv[k]);
        }
        __syncthreads();

        // ---- P3: numerator = a + Dh^T bh + Dv^T bv ----
        float numv[PXT];
        #pragma unroll 4
        for (int k = 0; k < PXT; ++k) {
            int p    = tid + k * NT;
            int col  = p & (NSIDE - 1);
            int rowb = p & ~(NSIDE - 1);
            int sc_  = SW(col);
            float bhr = C[rowb + SW((col + 1) & (NSIDE - 1))].x;
            int pd    = (p + NSIDE) & (NPIX - 1);
            float bvd = C[(pd & ~(NSIDE - 1)) + sc_].y;
            numv[k] = a[k] + (bh[k] - bhr) + (bv[k] - bvd);
        }
        __syncthreads();          // all neighbor reads done before overwrite

        // ---- P4: C <- numerator (real) ----
        #pragma unroll 4
        for (int k = 0; k < PXT; ++k) {
            int p = tid + k * NT;
            int col = p & (NSIDE - 1);
            int rowb = p & ~(NSIDE - 1);
            C[rowb + SW(col)] = make_float2(numv[k], 0.0f);
        }
        __syncthreads();

        // ================= forward FFT over rows =================
        // fused radix-4 passes: (s,s+1) for s=0,2; then radix-8 (s=4,5,6)
        #define FWD_ROW_PASS(S, L2)                                          \
        {                                                                    \
            _Pragma("unroll 2")                                              \
            for (int q = 0; q < 4; ++q) {                                    \
                int m   = tid + q * NT;                                      \
                int rb  = (m >> 5) << 7;                                     \
                int b   = m & 31;                                            \
                int j   = b & ((L2) - 1);                                    \
                int i0  = ((b & ~((L2) - 1)) << 2) | j;                      \
                int e0 = rb + SW(i0);                                        \
                int e1 = rb + SW(i0 + (L2));                                 \
                int e2 = rb + SW(i0 + 2*(L2));                               \
                int e3 = rb + SW(i0 + 3*(L2));                               \
                float2 w1 = TW[j << (S)];                                    \
                float2 w2 = cmul(w1, w1);                                    \
                float2 x0 = C[e0], x1 = C[e1];                               \
                float2 x2 = C[e2], x3 = C[e3];                               \
                float2 t02p = cadd(x0, x2);                                  \
                float2 t13p = cadd(x1, x3);                                  \
                float2 t02m = cmul(csub(x0, x2), w1);                        \
                float2 uu   = cmul(csub(x1, x3), w1);                        \
                float2 t13m = make_float2(uu.y, -uu.x);   /* * (-i) */       \
                C[e0] = cadd(t02p, t13p);                                    \
                C[e1] = cmul(csub(t02p, t13p), w2);                          \
                C[e2] = cadd(t02m, t13m);                                    \
                C[e3] = cmul(csub(t02m, t13m), w2);                          \
            }                                                                \
            __syncthreads();                                                 \
        }
        FWD_ROW_PASS(0, 32)
        FWD_ROW_PASS(2, 8)
        // radix-8 pass: stages 4,5,6 on 8 consecutive cols (const twiddles)
        {
            #pragma unroll 2
            for (int q = 0; q < 2; ++q) {
                int m  = tid + q * NT;          // 0..2047 group index
                int rb = (m >> 4) << 7;         // row*128
                int cb = (m & 15) << 3;         // base col
                float2 z[8];
                #pragma unroll
                for (int i = 0; i < 8; ++i) z[i] = C[rb + SW(cb + i)];
                radix8_fwd(z);
                #pragma unroll
                for (int i = 0; i < 8; ++i) C[rb + SW(cb + i)] = z[i];
            }
            __syncthreads();
        }

        // ================= forward FFT over cols (2 radix-4 passes) =======
        #define FWD_COL_PASS(S, L2)                                          \
        {                                                                    \
            _Pragma("unroll 2")                                              \
            for (int q = 0; q < 4; ++q) {                                    \
                int m  = tid + q * NT;                                       \
                int c  = m & 127;                                            \
                int b  = m >> 7;                                             \
                int j  = b & ((L2) - 1);                                     \
                int i0 = ((b & ~((L2) - 1)) << 2) | j;                       \
                int p0 = (i0 << 7) + SW(c);                                  \
                const int ST = (L2) << 7;                                    \
                float2 w1 = TW[j << (S)];                                    \
                float2 w2 = cmul(w1, w1);                                    \
                float2 x0 = C[p0], x1 = C[p0 + ST];                          \
                float2 x2 = C[p0 + 2*ST], x3 = C[p0 + 3*ST];                 \
                float2 t02p = cadd(x0, x2);                                  \
                float2 t13p = cadd(x1, x3);                                  \
                float2 t02m = cmul(csub(x0, x2), w1);                        \
                float2 uu   = cmul(csub(x1, x3), w1);                        \
                float2 t13m = make_float2(uu.y, -uu.x);                      \
                C[p0]        = cadd(t02p, t13p);                             \
                C[p0 +   ST] = cmul(csub(t02p, t13p), w2);                   \
                C[p0 + 2*ST] = cadd(t02m, t13m);                             \
                C[p0 + 3*ST] = cmul(csub(t02m, t13m), w2);                   \
            }                                                                \
            __syncthreads();                                                 \
        }
        FWD_COL_PASS(0, 32)
        FWD_COL_PASS(2, 8)

        // ==== MEGA-PASS: cols fwd radix-8 (s=4,5,6) + solve x8 +
        //      cols inverse radix-8 (s=0,1,2), all in registers ====
        {
            const float sc = 1.0f / (float)NPIX;
            #pragma unroll 2
            for (int q = 0; q < 2; ++q) {
                int m   = tid + q * NT;
                int col = m & 127;
                int g   = m >> 7;               // 0..15 row-group
                int r0  = g << 3;               // base row
                int p0  = (r0 << 7) + SW(col);
                float2 z[8];
                #pragma unroll
                for (int i = 0; i < 8; ++i) z[i] = C[p0 + (i << 7)];
                radix8_fwd(z);
                float d1c = D1[col];
                #pragma unroll
                for (int i = 0; i < 8; ++i) {
                    float f = sc / fmaf(mu2, D1[r0 + i] + d1c, mu1);
                    z[i].x *= f; z[i].y *= f;
                }
                radix8_inv(z);
                #pragma unroll
                for (int i = 0; i < 8; ++i) C[p0 + (i << 7)] = z[i];
            }
            __syncthreads();
        }

        // ================= inverse FFT over cols (2 radix-4 passes) =======
        // fused DIT pairs (s,s+1): (3,4) -> M=8,SB=2 ; (5,6) -> M=32,SB=0
        #define INV_COL_PASS(SB, M)                                          \
        {                                                                    \
            _Pragma("unroll 2")                                              \
            for (int q = 0; q < 4; ++q) {                                    \
                int m  = tid + q * NT;                                       \
                int c  = m & 127;                                            \
                int b  = m >> 7;                                             \
                int j  = b & ((M) - 1);                                      \
                int i0 = ((b & ~((M) - 1)) << 2) | j;                        \
                int p0 = (i0 << 7) + SW(c);                                  \
                const int ST = (M) << 7;                                     \
                float2 wb = TW[j << (SB)];                                   \
                float2 wa = cmul(wb, wb);                                    \
                float2 x0 = C[p0], x1 = C[p0 + ST];                          \
                float2 x2 = C[p0 + 2*ST], x3 = C[p0 + 3*ST];                 \
                float2 pp1 = cmulc(x1, wa);                                  \
                float2 a0 = cadd(x0, pp1), a1 = csub(x0, pp1);               \
                float2 pp2 = cmulc(x3, wa);                                  \
                float2 a2 = cadd(x2, pp2), a3 = csub(x2, pp2);               \
                float2 q0 = cmulc(a2, wb);                                   \
                float2 y0 = cadd(a0, q0), y2 = csub(a0, q0);                 \
                float2 uu = cmulc(a3, wb);                                   \
                float2 q1 = make_float2(-uu.y, uu.x);     /* * (+i) */       \
                float2 y1 = cadd(a1, q1), y3 = csub(a1, q1);                 \
                C[p0]        = y0;                                           \
                C[p0 +   ST] = y1;                                           \
                C[p0 + 2*ST] = y2;                                           \
                C[p0 + 3*ST] = y3;                                           \
            }                                                                \
            __syncthreads();                                                 \
        }
        INV_COL_PASS(2, 8)
        INV_COL_PASS(0, 32)

        // ================= inverse FFT over rows =================
        // radix-8 pass: stages 0,1,2 on 8 consecutive cols (const twiddles)
        {
            #pragma unroll 2
            for (int q = 0; q < 2; ++q) {
                int m  = tid + q * NT;
                int rb = (m >> 4) << 7;
                int cb = (m & 15) << 3;
                float2 z[8];
                #pragma unroll
                for (int i = 0; i < 8; ++i) z[i] = C[rb + SW(cb + i)];
                radix8_inv(z);
                #pragma unroll
                for (int i = 0; i < 8; ++i) C[rb + SW(cb + i)] = z[i];
            }
            __syncthreads();
        }
        #define INV_ROW_PASS(SB, M)                                          \
        {                                                                    \
            _Pragma("unroll 2")                                              \
            for (int q = 0; q < 4; ++q) {                                    \
                int m   = tid + q * NT;                                      \
                int rb  = (m >> 5) << 7;                                     \
                int b   = m & 31;                                            \
                int j   = b & ((M) - 1);                                     \
                int i0  = ((b & ~((M) - 1)) << 2) | j;                       \
                int e0 = rb + SW(i0);                                        \
                int e1 = rb + SW(i0 + (M));                                  \
                int e2 = rb + SW(i0 + 2*(M));                                \
                int e3 = rb + SW(i0 + 3*(M));                                \
                float2 wb = TW[j << (SB)];                                   \
                float2 wa = cmul(wb, wb);                                    \
                float2 x0 = C[e0], x1 = C[e1];                               \
                float2 x2 = C[e2], x3 = C[e3];                               \
                float2 pp1 = cmulc(x1, wa);                                  \
                float2 a0 = cadd(x0, pp1), a1 = csub(x0, pp1);               \
                float2 pp2 = cmulc(x3, wa);                                  \
                float2 a2 = cadd(x2, pp2), a3 = csub(x2, pp2);               \
                float2 q0 = cmulc(a2, wb);                                   \
                float2 y0 = cadd(a0, q0), y2 = csub(a0, q0);                 \
                float2 uu = cmulc(a3, wb);                                   \
                float2 q1 = make_float2(-uu.y, uu.x);                        \
                float2 y1 = cadd(a1, q1), y3 = csub(a1, q1);                 \
                C[e0] = y0;                                                  \
                C[e1] = y1;                                                  \
                C[e2] = y2;                                                  \
                C[e3] = y3;                                                  \
            }                                                                \
            __syncthreads();                                                 \
        }
        INV_ROW_PASS(2, 8)
        INV_ROW_PASS(0, 32)

        // ---- Epilogue: X/G1/a update in registers; Z stays in C[].x ----
        const float mu1n = mu1 * RHO_F;
        #pragma unroll 4
        for (int k = 0; k < PXT; ++k) {
            int p = tid + k * NT;
            int col = p & (NSIDE - 1);
            int rowb = p & ~(NSIDE - 1);
            float z  = C[rowb + SW(col)].x;
            float y  = Y[p];
            float w  = Wt[p];
            float x  = fmaf(w, y, fmaf(mu1, z, -g1[k])) *
                       __builtin_amdgcn_rcpf(w + mu1);
            g1[k] = fmaf(mu1, x - z, g1[k]);
            a[k]  = fmaf(mu1n, x, g1[k]);
            if (it == N_ITE - 1) out[p] = z;
        }
        // no barrier needed: next P1 only reads C (covered by the FFT's last
        // barrier); P2's writes are behind P1's barrier.

        mu1 *= RHO_F;
        mu2 *= RHO_F;
    }
}

extern "C" void kernel_launch(void* const* d_in, const int* in_sizes, int n_in,
                              void* d_out, int out_size, void* d_ws, size_t ws_size,
                              hipStream_t stream) {
    (void)in_sizes; (void)n_in; (void)out_size; (void)d_ws; (void)ws_size;
    const float* Y   = (const float*)d_in[0];
    const float* inW = (const float*)d_in[1];
    float* out = (float*)d_out;

    const size_t smem_bytes = (size_t)NPIX * 8 + 64 * 8 + 128 * 4;  // 132096
    hipFuncSetAttribute((const void*)hwtv_kernel,
                        hipFuncAttributeMaxDynamicSharedMemorySize,
                        (int)smem_bytes);
    hipLaunchKernelGGL(hwtv_kernel, dim3(NIMG), dim3(NT), smem_bytes, stream,
                       Y, inW, out);
}